// Round 3
// baseline (591.967 us; speedup 1.0000x reference)
//
#include <hip/hip_runtime.h>

typedef unsigned short u16;
typedef unsigned int u32;
typedef _Float16 f16x8 __attribute__((ext_vector_type(8)));
typedef float f32x4 __attribute__((ext_vector_type(4)));

#define LDST 40  // LDS row stride in u16 (80B): b128 rows hit distinct bank phases, 2-way max -> free

// ---------- scalar converters ----------
__device__ __forceinline__ float bf2f(u16 v) {
  union { u32 u; float f; } c; c.u = ((u32)v) << 16; return c.f;
}
__device__ __forceinline__ u16 f2bf(float f) {
  union { float f; u32 u; } c; c.f = f;
  u32 u = c.u;
  return (u16)((u + 0x7fffu + ((u >> 16) & 1u)) >> 16);  // RNE
}
__device__ __forceinline__ u16 f2h(float f) {
  union { _Float16 h; u16 u; } c; c.h = (_Float16)f; return c.u;
}
__device__ __forceinline__ float h2f(u16 v) {
  union { u16 u; _Float16 h; } c; c.u = v; return (float)c.h;
}
// mode: 0 = bf16, 1 = fp32, 2 = fp16
__device__ __forceinline__ float ldf(const void* b, size_t i, int mode) {
  if (mode == 1) return ((const float*)b)[i];
  u16 w = ((const u16*)b)[i];
  return mode == 0 ? bf2f(w) : h2f(w);
}
// 8 contiguous elements at elem-index i (i % 8 == 0) -> 8 fp16 (u16)
__device__ __forceinline__ void ld8(const void* base, size_t i, int mode, u16* o) {
  if (mode == 1) {
    const float* s = (const float*)base + i;
    float4 a = *(const float4*)s;
    float4 b = *(const float4*)(s + 4);
    o[0] = f2h(a.x); o[1] = f2h(a.y); o[2] = f2h(a.z); o[3] = f2h(a.w);
    o[4] = f2h(b.x); o[5] = f2h(b.y); o[6] = f2h(b.z); o[7] = f2h(b.w);
  } else if (mode == 0) {
    u16 t[8]; *(int4*)t = *(const int4*)((const u16*)base + i);
#pragma unroll
    for (int e = 0; e < 8; ++e) o[e] = f2h(bf2f(t[e]));
  } else {
    *(int4*)o = *(const int4*)((const u16*)base + i);
  }
}

__device__ __forceinline__ f32x4 mfma16(f16x8 a, f16x8 b, f32x4 c) {
  return __builtin_amdgcn_mfma_f32_16x16x32_f16(a, b, c, 0, 0, 0);
}

// NT tile core: C[BM,BN] += A[BM,K] * B[BN,K]^T. Operands given as raw base + element offset,
// amode/bmode select dtype (2 = fp16 passthrough). NNB=true: B is [K][BN] row-major ->
// transpose-staged into LDS with xor-8 swizzle (BN must be 128). BM=TM*32, BN=TN*32. 256 thr.
template<int TM, int TN, bool NNB>
__device__ __forceinline__ void gemm_core(const void* A, size_t aoff, int lda, int amode,
                                          const void* B, size_t boff, int ldb, int bmode,
                                          int ksteps, u16* sA, u16* sB, f32x4 acc[TM][TN]) {
  const int t = threadIdx.x;
  const int lane = t & 63, wave = t >> 6;
  const int wm = wave >> 1, wn = wave & 1;
  const int m16 = lane & 15, q4 = lane >> 4;
  constexpr int BM = TM * 32, BN = TN * 32;

  for (int kt = 0; kt < ksteps; ++kt) {
    __syncthreads();
#pragma unroll
    for (int p = 0; p < BM / 64; ++p) {
      int flat = (p * 256 + t) * 8;
      int row = flat >> 5, col = flat & 31;
      u16 o[8];
      ld8(A, aoff + (size_t)row * lda + col, amode, o);
      *(int4*)&sA[row * LDST + col] = *(int4*)o;
    }
    if constexpr (!NNB) {
#pragma unroll
      for (int p = 0; p < BN / 64; ++p) {
        int flat = (p * 256 + t) * 8;
        int row = flat >> 5, col = flat & 31;
        u16 o[8];
        ld8(B, boff + (size_t)row * ldb + col, bmode, o);
        *(int4*)&sB[row * LDST + col] = *(int4*)o;
      }
    } else {
      // stage B[k][n] tile (32 x 128) transposed into sB[n][k^swz]
      int kk = (t >> 4) * 2, nn = (t & 15) * 8;
      u16 a0[8], a1[8];
      ld8(B, boff + (size_t)kk * ldb + nn, bmode, a0);
      ld8(B, boff + (size_t)(kk + 1) * ldb + nn, bmode, a1);
#pragma unroll
      for (int e = 0; e < 8; ++e) {
        int n = nn + e;
        int kf = kk ^ (((n >> 3) & 3) << 3);
        *(u32*)&sB[n * LDST + kf] = (u32)a0[e] | ((u32)a1[e] << 16);
      }
    }
    __syncthreads();

    f16x8 af[TM], bv[TN];
#pragma unroll
    for (int i = 0; i < TM; ++i)
      af[i] = *(const f16x8*)&sA[(wm * TM * 16 + i * 16 + m16) * LDST + q4 * 8];
#pragma unroll
    for (int j = 0; j < TN; ++j) {
      int n = wn * TN * 16 + j * 16 + m16;
      int kf = NNB ? ((q4 * 8) ^ (((n >> 3) & 3) << 3)) : (q4 * 8);
      bv[j] = *(const f16x8*)&sB[n * LDST + kf];
    }
#pragma unroll
    for (int i = 0; i < TM; ++i)
#pragma unroll
      for (int j = 0; j < TN; ++j)
        acc[i][j] = mfma16(af[i], bv[j], acc[i][j]);

    aoff += 32;
    boff += NNB ? (size_t)32 * ldb : (size_t)32;
  }
}

// ---------- dtype detection ----------
// flag[0]: count of bf16-NaN bit patterns among even-indexed u16 halves (fp32 -> thousands)
// flag[1]: count of |bf16-interp| >= 8 (fp16 data -> tens of thousands; genuine bf16 N(0,1) -> 0)
// flag[2]: decided mode
__global__ __launch_bounds__(256) void detect_kernel(const u16* __restrict__ x, int* __restrict__ flag) {
  int i = blockIdx.x * 256 + threadIdx.x;  // < 1<<20
  u16 w = x[2 * i];
  int ef = (w >> 7) & 0xFF;
  unsigned long long mn = __ballot(ef == 0xFF);
  unsigned long long mb = __ballot(ef >= 130);
  if ((threadIdx.x & 63) == 0) {
    if (mn) atomicAdd(&flag[0], (int)__popcll(mn));
    if (mb) atomicAdd(&flag[1], (int)__popcll(mb));
  }
}
__global__ void decide_kernel(int* __restrict__ flag) {
  flag[2] = flag[0] > 64 ? 1 : (flag[1] > 256 ? 2 : 0);
}

// qs[j] = sum_n q[j,n]
__global__ __launch_bounds__(256) void qs_kernel(const void* __restrict__ q, float* __restrict__ qs,
                                                 const int* __restrict__ flag) {
  int mode = flag[2];
  int row = blockIdx.x, t = threadIdx.x;
  float s = 0.f;
#pragma unroll
  for (int p = 0; p < 2; ++p) {
    u16 o[8];
    ld8(q, (size_t)row * 4096 + p * 2048 + t * 8, mode, o);
#pragma unroll
    for (int e = 0; e < 8; ++e) s += h2f(o[e]);
  }
  for (int off = 32; off; off >>= 1) s += __shfl_xor(s, off);
  __shared__ float wsum[4];
  if ((t & 63) == 0) wsum[t >> 6] = s;
  __syncthreads();
  if (t == 0) qs[row] = wsum[0] + wsum[1] + wsum[2] + wsum[3];
}

__global__ __launch_bounds__(256) void cvt_kw_kernel(const void* __restrict__ kw, u16* __restrict__ kwh,
                                                     const int* __restrict__ flag) {
  int mode = flag[2];
  size_t i = ((size_t)blockIdx.x * 256 + threadIdx.x) * 8;
  u16 o[8];
  ld8(kw, i, mode, o);
  *(int4*)&kwh[i] = *(int4*)o;
}

__global__ __launch_bounds__(256) void cvt_bias_kernel(const void* __restrict__ kb, const void* __restrict__ vb,
                                                       const void* __restrict__ gm, float* __restrict__ kbf,
                                                       float* __restrict__ vbf, float* __restrict__ gmf,
                                                       const int* __restrict__ flag) {
  int mode = flag[2];
  int t = threadIdx.x;
  for (int i = t; i < 512; i += 256) {
    kbf[i] = ldf(kb, i, mode);
    vbf[i] = ldf(vb, i, mode);
  }
  if (t == 0) gmf[0] = ldf(gm, 0, mode);
}

// vwT[o][x] = fp16(value_w[x][o])
__global__ __launch_bounds__(256) void transpose_cvt_kernel(const void* __restrict__ vw, u16* __restrict__ vwT,
                                                            const int* __restrict__ flag) {
  int mode = flag[2];
  __shared__ u16 sT[32 * 33];
  int bx = blockIdx.x, by = blockIdx.y, t = threadIdx.x;
#pragma unroll
  for (int p = 0; p < 4; ++p) {
    int idx = p * 256 + t; int r = idx >> 5, c = idx & 31;
    sT[r * 33 + c] = f2h(ldf(vw, (size_t)(by * 32 + r) * 512 + bx * 32 + c, mode));
  }
  __syncthreads();
#pragma unroll
  for (int p = 0; p < 4; ++p) {
    int idx = p * 256 + t; int r = idx >> 5, c = idx & 31;
    vwT[(size_t)(bx * 32 + r) * 512 + by * 32 + c] = sT[c * 33 + r];
  }
}

// Sh[b][y][o] = sum_n q[y,n]*x[(b,o),n]; 64x64 tiles, K=4096, raw operands converted in staging
__global__ __launch_bounds__(256) void sgemm_kernel(const void* __restrict__ q, const void* __restrict__ x,
                                                    u16* __restrict__ Sh, const int* __restrict__ flag) {
  int mode = flag[2];
  __shared__ u16 sA[64 * LDST], sB[64 * LDST];
  int rt = blockIdx.x, jt = blockIdx.y;
  f32x4 acc[2][2];
#pragma unroll
  for (int i = 0; i < 2; ++i)
#pragma unroll
    for (int j = 0; j < 2; ++j) acc[i][j] = (f32x4){0.f, 0.f, 0.f, 0.f};
  gemm_core<2, 2, false>(q, (size_t)jt * 64 * 4096, 4096, mode,
                         x, (size_t)rt * 64 * 4096, 4096, mode, 128, sA, sB, acc);

  const int t = threadIdx.x, lane = t & 63, wave = t >> 6;
  const int wm = wave >> 1, wn = wave & 1, m16 = lane & 15, q4 = lane >> 4;
  int b = (rt * 64) >> 9, o0 = (rt * 64) & 511;
  u16* Ob = Sh + (size_t)b * 262144;
#pragma unroll
  for (int i = 0; i < 2; ++i)
#pragma unroll
    for (int j = 0; j < 2; ++j)
#pragma unroll
      for (int r = 0; r < 4; ++r) {
        int y = jt * 64 + wm * 32 + i * 16 + q4 * 4 + r;
        int o = o0 + wn * 32 + j * 16 + m16;
        Ob[(size_t)y * 512 + o] = f2h(acc[i][j][r]);
      }
}

// E[b,x,y] = sum_o kw[x,o] * Sh[b][y][o]
__global__ __launch_bounds__(256) void egemm_kernel(const u16* __restrict__ kwh, const u16* __restrict__ Sh,
                                                    float* __restrict__ E) {
  __shared__ u16 sA[64 * LDST], sB[64 * LDST];
  int xt = blockIdx.x >> 3, yt = blockIdx.x & 7, b = blockIdx.y;
  f32x4 acc[2][2];
#pragma unroll
  for (int i = 0; i < 2; ++i)
#pragma unroll
    for (int j = 0; j < 2; ++j) acc[i][j] = (f32x4){0.f, 0.f, 0.f, 0.f};
  gemm_core<2, 2, false>(kwh, (size_t)xt * 64 * 512, 512, 2,
                         Sh, (size_t)b * 262144 + (size_t)yt * 64 * 512, 512, 2, 16, sA, sB, acc);

  const int t = threadIdx.x, lane = t & 63, wave = t >> 6;
  const int wm = wave >> 1, wn = wave & 1, m16 = lane & 15, q4 = lane >> 4;
  float* O = E + ((size_t)b * 512 + xt * 64) * 512 + yt * 64;
#pragma unroll
  for (int i = 0; i < 2; ++i)
#pragma unroll
    for (int j = 0; j < 2; ++j)
#pragma unroll
      for (int r = 0; r < 4; ++r) {
        int row = wm * 32 + i * 16 + q4 * 4 + r;
        int col = wn * 32 + j * 16 + m16;
        O[(size_t)row * 512 + col] = acc[i][j][r];
      }
}

// softmax over y of (E[b,x,y]+kb[x]*qs[y]); writes attT[b][y][x] fp16; beta[b][y] += sum_x att*vb[x]
__global__ __launch_bounds__(256) void softmax_kernel(const float* __restrict__ E, const float* __restrict__ qs,
                                                      const float* __restrict__ kbf, const float* __restrict__ vbf,
                                                      u16* __restrict__ attT, float* __restrict__ beta) {
  __shared__ float sE[16 * 516];
  __shared__ float sM[16], sS[16];
  int i0 = blockIdx.x * 16, b = blockIdx.y, t = threadIdx.x;
  const float* Eb = E + ((size_t)b * 512 + i0) * 512;
  for (int ch = 0; ch < 32; ++ch) {
    int idx = ch * 256 + t;
    int row = idx >> 9, col = idx & 511;
    sE[row * 516 + col] = Eb[(size_t)row * 512 + col] + kbf[i0 + row] * qs[col];
  }
  __syncthreads();
  {
    int row = t >> 4, sub = t & 15;
    float mx = -1e30f;
    for (int ii = 0; ii < 32; ++ii) mx = fmaxf(mx, sE[row * 516 + sub + ii * 16]);
    for (int off = 8; off; off >>= 1) mx = fmaxf(mx, __shfl_xor(mx, off));
    float sm = 0.f;
    for (int ii = 0; ii < 32; ++ii) sm += __expf(sE[row * 516 + sub + ii * 16] - mx);
    for (int off = 8; off; off >>= 1) sm += __shfl_xor(sm, off);
    if (sub == 0) { sM[row] = mx; sS[row] = 1.f / sm; }
  }
  __syncthreads();
  float vbr = vbf[i0 + (t & 15)];
  u16* Ob = attT + (size_t)b * 262144;
  for (int ch = 0; ch < 32; ++ch) {
    int idx = ch * 256 + t;
    int r = idx & 15, j = idx >> 4;
    float a = __expf(sE[r * 516 + j] - sM[r]) * sS[r];
    Ob[(size_t)j * 512 + i0 + r] = f2h(a);
    float part = a * vbr;
    for (int off = 8; off; off >>= 1) part += __shfl_xor(part, off);
    if (r == 0) atomicAdd(&beta[b * 512 + j], part);
  }
}

// W[b][c][o] = sum_x attT[b][c][x] * vwT[o][x]
__global__ __launch_bounds__(256) void wgemm_kernel(const u16* __restrict__ attT, const u16* __restrict__ vwT,
                                                    u16* __restrict__ W) {
  __shared__ u16 sA[64 * LDST], sB[64 * LDST];
  int ct = blockIdx.x >> 3, ot = blockIdx.x & 7, b = blockIdx.y;
  f32x4 acc[2][2];
#pragma unroll
  for (int i = 0; i < 2; ++i)
#pragma unroll
    for (int j = 0; j < 2; ++j) acc[i][j] = (f32x4){0.f, 0.f, 0.f, 0.f};
  gemm_core<2, 2, false>(attT, (size_t)b * 262144 + (size_t)ct * 64 * 512, 512, 2,
                         vwT, (size_t)ot * 64 * 512, 512, 2, 16, sA, sB, acc);

  const int t = threadIdx.x, lane = t & 63, wave = t >> 6;
  const int wm = wave >> 1, wn = wave & 1, m16 = lane & 15, q4 = lane >> 4;
  u16* O = W + (size_t)b * 262144 + (size_t)(ct * 64) * 512 + ot * 64;
#pragma unroll
  for (int i = 0; i < 2; ++i)
#pragma unroll
    for (int j = 0; j < 2; ++j)
#pragma unroll
      for (int r = 0; r < 4; ++r) {
        int row = wm * 32 + i * 16 + q4 * 4 + r;
        int col = wn * 32 + j * 16 + m16;
        O[(size_t)row * 512 + col] = f2h(acc[i][j][r]);
      }
}

// out[b,c,n] = enc( gamma*(sum_o W[b,c,o]*x[b,o,n] + beta[b,c]) + x[b,c,n] ), enc per detected dtype
__global__ __launch_bounds__(256) void outgemm_kernel(const u16* __restrict__ W, const void* __restrict__ x,
                                                      const float* __restrict__ beta, const float* __restrict__ gmf,
                                                      void* __restrict__ out, const int* __restrict__ flag) {
  int mode = flag[2];
  __shared__ u16 sA[128 * LDST], sB[128 * LDST];
  int nt = blockIdx.x, ct = blockIdx.y, b = blockIdx.z;
  f32x4 acc[4][4];
#pragma unroll
  for (int i = 0; i < 4; ++i)
#pragma unroll
    for (int j = 0; j < 4; ++j) acc[i][j] = (f32x4){0.f, 0.f, 0.f, 0.f};
  gemm_core<4, 4, true>(W, (size_t)b * 262144 + (size_t)ct * 128 * 512, 512, 2,
                        x, (size_t)b * 2097152 + nt * 128, 4096, mode, 16, sA, sB, acc);

  const int t = threadIdx.x, lane = t & 63, wave = t >> 6;
  const int wm = wave >> 1, wn = wave & 1, m16 = lane & 15, q4 = lane >> 4;
  float g = gmf[0];
#pragma unroll
  for (int i = 0; i < 4; ++i)
#pragma unroll
    for (int j = 0; j < 4; ++j)
#pragma unroll
      for (int r = 0; r < 4; ++r) {
        int c = ct * 128 + wm * 64 + i * 16 + q4 * 4 + r;
        int n = nt * 128 + wn * 64 + j * 16 + m16;
        size_t idx = (size_t)b * 2097152 + (size_t)c * 4096 + n;
        float val = g * (acc[i][j][r] + beta[b * 512 + c]) + ldf(x, idx, mode);
        if (mode == 1) ((float*)out)[idx] = val;
        else ((u16*)out)[idx] = (mode == 0) ? f2bf(val) : f2h(val);
      }
}

extern "C" void kernel_launch(void* const* d_in, const int* in_sizes, int n_in,
                              void* d_out, int out_size, void* d_ws, size_t ws_size,
                              hipStream_t stream) {
  const void* x  = d_in[0];
  const void* pq = d_in[1];
  const void* kw = d_in[2];
  const void* kb = d_in[3];
  const void* vb = d_in[5];
  const void* vw = d_in[4];
  const void* gm = d_in[6];

  // compact workspace: 17 MB + 32 KB total
  char* ws = (char*)d_ws;
  u16*   Sh   = (u16*)(ws);                            // [0,4M)  S fp16; reused as W after egemm
  u16*   W    = (u16*)(ws);
  float* E    = (float*)(ws + (4ull << 20));           // [4,12M) fp32
  u16*   attT = (u16*)(ws + (12ull << 20));            // [12,16M)
  u16*   kwh  = (u16*)(ws + (16ull << 20));            // 512K
  u16*   vwT  = (u16*)(ws + (16ull << 20) + 524288);   // 512K
  char*  sm   = ws + (17ull << 20);                    // 32K small region
  int*   flag = (int*)(sm);
  float* kbf  = (float*)(sm + 1024);
  float* vbf  = (float*)(sm + 3072);
  float* gmf  = (float*)(sm + 5120);
  float* qs   = (float*)(sm + 6144);
  float* beta = (float*)(sm + 8192);                   // 16K

  hipMemsetAsync(sm, 0, 32768, stream);
  detect_kernel<<<dim3(4096), 256, 0, stream>>>((const u16*)x, flag);
  decide_kernel<<<dim3(1), 1, 0, stream>>>(flag);
  qs_kernel<<<dim3(512), 256, 0, stream>>>(pq, qs, flag);
  cvt_kw_kernel<<<dim3(128), 256, 0, stream>>>(kw, kwh, flag);
  cvt_bias_kernel<<<dim3(1), 256, 0, stream>>>(kb, vb, gm, kbf, vbf, gmf, flag);
  transpose_cvt_kernel<<<dim3(16, 16), 256, 0, stream>>>(vw, vwT, flag);
  sgemm_kernel<<<dim3(64, 8), 256, 0, stream>>>(pq, x, Sh, flag);
  egemm_kernel<<<dim3(64, 8), 256, 0, stream>>>(kwh, Sh, E);
  softmax_kernel<<<dim3(32, 8), 256, 0, stream>>>(E, qs, kbf, vbf, attT, beta);
  wgemm_kernel<<<dim3(64, 8), 256, 0, stream>>>(attT, vwT, W);
  outgemm_kernel<<<dim3(32, 4, 8), 256, 0, stream>>>(W, x, beta, gmf, d_out, flag);
}

// Round 4
// 262.718 us; speedup vs baseline: 2.2532x; 2.2532x over previous
//
#include <hip/hip_runtime.h>

typedef unsigned short u16;
typedef unsigned int u32;
typedef _Float16 f16x8 __attribute__((ext_vector_type(8)));
typedef float f32x4 __attribute__((ext_vector_type(4)));

#define LDST 40  // LDS row stride in u16 (80B): b128 rows land on distinct bank phases, 2-way max -> free

__device__ __forceinline__ u16 f2h(float f) {
  union { _Float16 h; u16 u; } c; c.h = (_Float16)f; return c.u;
}
__device__ __forceinline__ float h2f(u16 v) {
  union { u16 u; _Float16 h; } c; c.u = v; return (float)c.h;
}

__device__ __forceinline__ f32x4 mfma16(f16x8 a, f16x8 b, f32x4 c) {
  return __builtin_amdgcn_mfma_f32_16x16x32_f16(a, b, c, 0, 0, 0);
}

// 8 contiguous fp32 -> 8 fp16 (u16)
__device__ __forceinline__ void ld8f(const float* s, u16* o) {
  float4 a = *(const float4*)s;
  float4 b = *(const float4*)(s + 4);
  o[0] = f2h(a.x); o[1] = f2h(a.y); o[2] = f2h(a.z); o[3] = f2h(a.w);
  o[4] = f2h(b.x); o[5] = f2h(b.y); o[6] = f2h(b.z); o[7] = f2h(b.w);
}

// NT tile core: C[BM,BN] += A[BM,K] * B[BN,K]^T, fp16-in-u16, K-contiguous (lda/ldb elems).
// NNB=true: B is [K][BN] row-major -> LDS transpose staging w/ xor-8 swizzle (BN must be 128).
// BM=TM*32, BN=TN*32 (2x2 waves, TMxTN 16x16 mfma tiles per wave). 256 threads.
template<int TM, int TN, bool NNB>
__device__ __forceinline__ void gemm_core(const u16* A, int lda, const u16* B, int ldb,
                                          int ksteps, u16* sA, u16* sB, f32x4 acc[TM][TN]) {
  const int t = threadIdx.x;
  const int lane = t & 63, wave = t >> 6;
  const int wm = wave >> 1, wn = wave & 1;
  const int m16 = lane & 15, q4 = lane >> 4;
  constexpr int BM = TM * 32, BN = TN * 32;

  for (int kt = 0; kt < ksteps; ++kt) {
    __syncthreads();
#pragma unroll
    for (int p = 0; p < BM / 64; ++p) {
      int flat = (p * 256 + t) * 8;
      int row = flat >> 5, col = flat & 31;
      *(int4*)&sA[row * LDST + col] = *(const int4*)&A[(size_t)row * lda + col];
    }
    if constexpr (!NNB) {
#pragma unroll
      for (int p = 0; p < BN / 64; ++p) {
        int flat = (p * 256 + t) * 8;
        int row = flat >> 5, col = flat & 31;
        *(int4*)&sB[row * LDST + col] = *(const int4*)&B[(size_t)row * ldb + col];
      }
    } else {
      // stage B[k][n] tile (32x128) transposed into sB[n][k^swz]
      int kk = (t >> 4) * 2, nn = (t & 15) * 8;
      const u16* src = B + (size_t)kk * ldb + nn;
      u16 a0[8], a1[8];
      *(int4*)a0 = *(const int4*)src;
      *(int4*)a1 = *(const int4*)(src + ldb);
#pragma unroll
      for (int e = 0; e < 8; ++e) {
        int n = nn + e;
        int kf = kk ^ (((n >> 3) & 3) << 3);
        *(u32*)&sB[n * LDST + kf] = (u32)a0[e] | ((u32)a1[e] << 16);
      }
    }
    __syncthreads();

    f16x8 af[TM], bv[TN];
#pragma unroll
    for (int i = 0; i < TM; ++i)
      af[i] = *(const f16x8*)&sA[(wm * TM * 16 + i * 16 + m16) * LDST + q4 * 8];
#pragma unroll
    for (int j = 0; j < TN; ++j) {
      int n = wn * TN * 16 + j * 16 + m16;
      int kf = NNB ? ((q4 * 8) ^ (((n >> 3) & 3) << 3)) : (q4 * 8);
      bv[j] = *(const f16x8*)&sB[n * LDST + kf];
    }
#pragma unroll
    for (int i = 0; i < TM; ++i)
#pragma unroll
      for (int j = 0; j < TN; ++j)
        acc[i][j] = mfma16(af[i], bv[j], acc[i][j]);

    A += 32;
    B += NNB ? (size_t)32 * ldb : (size_t)32;
  }
}

// x (fp32, 16.7M) -> xh (fp16)
__global__ __launch_bounds__(256) void cvt_x_kernel(const float* __restrict__ x, u16* __restrict__ xh) {
  size_t i = ((size_t)blockIdx.x * 256 + threadIdx.x) * 8;
  u16 o[8];
  ld8f(x + i, o);
  *(int4*)&xh[i] = *(int4*)o;
}

// q -> qh fp16 + qs row sums; one block per row
__global__ __launch_bounds__(256) void cvt_q_kernel(const float* __restrict__ q, u16* __restrict__ qh,
                                                    float* __restrict__ qs) {
  int row = blockIdx.x, t = threadIdx.x;
  float s = 0.f;
#pragma unroll
  for (int p = 0; p < 2; ++p) {
    size_t i = (size_t)row * 4096 + p * 2048 + t * 8;
    u16 o[8];
    ld8f(q + i, o);
#pragma unroll
    for (int e = 0; e < 8; ++e) s += h2f(o[e]);
    *(int4*)&qh[i] = *(int4*)o;
  }
  for (int off = 32; off; off >>= 1) s += __shfl_xor(s, off);
  __shared__ float wsum[4];
  if ((t & 63) == 0) wsum[t >> 6] = s;
  __syncthreads();
  if (t == 0) qs[row] = wsum[0] + wsum[1] + wsum[2] + wsum[3];
}

// multi-role prep: blocks [0,256): vwT[o][x]=fp16(vw[x][o]); [256,384): kw->fp16; 384: beta=0
__global__ __launch_bounds__(256) void prep_kernel(const float* __restrict__ vw, u16* __restrict__ vwT,
                                                   const float* __restrict__ kw, u16* __restrict__ kwh,
                                                   float* __restrict__ beta) {
  int blk = blockIdx.x, t = threadIdx.x;
  if (blk < 256) {
    __shared__ u16 sT[32 * 33];
    int bx = blk & 15, by = blk >> 4;
#pragma unroll
    for (int p = 0; p < 4; ++p) {
      int idx = p * 256 + t; int r = idx >> 5, c = idx & 31;
      sT[r * 33 + c] = f2h(vw[(size_t)(by * 32 + r) * 512 + bx * 32 + c]);
    }
    __syncthreads();
#pragma unroll
    for (int p = 0; p < 4; ++p) {
      int idx = p * 256 + t; int r = idx >> 5, c = idx & 31;
      vwT[(size_t)(bx * 32 + r) * 512 + by * 32 + c] = sT[c * 33 + r];
    }
  } else if (blk < 384) {
    size_t i = ((size_t)(blk - 256) * 256 + t) * 8;
    u16 o[8];
    ld8f(kw + i, o);
    *(int4*)&kwh[i] = *(int4*)o;
  } else {
    for (int i = t; i < 4096; i += 256) beta[i] = 0.f;
  }
}

// Sh[b][y][o] = sum_n q[y,n]*x[(b,o),n]; 64x64 tiles, K=4096
__global__ __launch_bounds__(256) void sgemm_kernel(const u16* __restrict__ qh, const u16* __restrict__ xh,
                                                    u16* __restrict__ Sh) {
  __shared__ u16 sA[64 * LDST], sB[64 * LDST];
  int rt = blockIdx.x, jt = blockIdx.y;
  f32x4 acc[2][2];
#pragma unroll
  for (int i = 0; i < 2; ++i)
#pragma unroll
    for (int j = 0; j < 2; ++j) acc[i][j] = (f32x4){0.f, 0.f, 0.f, 0.f};
  gemm_core<2, 2, false>(qh + (size_t)jt * 64 * 4096, 4096,
                         xh + (size_t)rt * 64 * 4096, 4096, 128, sA, sB, acc);

  const int t = threadIdx.x, lane = t & 63, wave = t >> 6;
  const int wm = wave >> 1, wn = wave & 1, m16 = lane & 15, q4 = lane >> 4;
  int b = (rt * 64) >> 9, o0 = (rt * 64) & 511;
  u16* Ob = Sh + (size_t)b * 262144;
#pragma unroll
  for (int i = 0; i < 2; ++i)
#pragma unroll
    for (int j = 0; j < 2; ++j)
#pragma unroll
      for (int r = 0; r < 4; ++r) {
        int y = jt * 64 + wm * 32 + i * 16 + q4 * 4 + r;
        int o = o0 + wn * 32 + j * 16 + m16;
        Ob[(size_t)y * 512 + o] = f2h(acc[i][j][r]);
      }
}

// E[b,x,y] = sum_o kw[x,o] * Sh[b][y][o]
__global__ __launch_bounds__(256) void egemm_kernel(const u16* __restrict__ kwh, const u16* __restrict__ Sh,
                                                    float* __restrict__ E) {
  __shared__ u16 sA[64 * LDST], sB[64 * LDST];
  int xt = blockIdx.x >> 3, yt = blockIdx.x & 7, b = blockIdx.y;
  f32x4 acc[2][2];
#pragma unroll
  for (int i = 0; i < 2; ++i)
#pragma unroll
    for (int j = 0; j < 2; ++j) acc[i][j] = (f32x4){0.f, 0.f, 0.f, 0.f};
  gemm_core<2, 2, false>(kwh + (size_t)xt * 64 * 512, 512,
                         Sh + (size_t)b * 262144 + (size_t)yt * 64 * 512, 512, 16, sA, sB, acc);

  const int t = threadIdx.x, lane = t & 63, wave = t >> 6;
  const int wm = wave >> 1, wn = wave & 1, m16 = lane & 15, q4 = lane >> 4;
  float* O = E + ((size_t)b * 512 + xt * 64) * 512 + yt * 64;
#pragma unroll
  for (int i = 0; i < 2; ++i)
#pragma unroll
    for (int j = 0; j < 2; ++j)
#pragma unroll
      for (int r = 0; r < 4; ++r) {
        int row = wm * 32 + i * 16 + q4 * 4 + r;
        int col = wn * 32 + j * 16 + m16;
        O[(size_t)row * 512 + col] = acc[i][j][r];
      }
}

// softmax over y of (E[b,x,y]+kb[x]*qs[y]); writes attT[b][y][x] fp16; beta[b][y] += sum_x att*vb[x]
__global__ __launch_bounds__(256) void softmax_kernel(const float* __restrict__ E, const float* __restrict__ qs,
                                                      const float* __restrict__ kb, const float* __restrict__ vb,
                                                      u16* __restrict__ attT, float* __restrict__ beta) {
  __shared__ float sE[16 * 516];
  __shared__ float sM[16], sS[16];
  int i0 = blockIdx.x * 16, b = blockIdx.y, t = threadIdx.x;
  const float* Eb = E + ((size_t)b * 512 + i0) * 512;
  for (int ch = 0; ch < 32; ++ch) {
    int idx = ch * 256 + t;
    int row = idx >> 9, col = idx & 511;
    sE[row * 516 + col] = Eb[(size_t)row * 512 + col] + kb[i0 + row] * qs[col];
  }
  __syncthreads();
  {
    int row = t >> 4, sub = t & 15;
    float mx = -1e30f;
    for (int ii = 0; ii < 32; ++ii) mx = fmaxf(mx, sE[row * 516 + sub + ii * 16]);
    for (int off = 8; off; off >>= 1) mx = fmaxf(mx, __shfl_xor(mx, off));
    float sm = 0.f;
    for (int ii = 0; ii < 32; ++ii) sm += __expf(sE[row * 516 + sub + ii * 16] - mx);
    for (int off = 8; off; off >>= 1) sm += __shfl_xor(sm, off);
    if (sub == 0) { sM[row] = mx; sS[row] = 1.f / sm; }
  }
  __syncthreads();
  float vbr = vb[i0 + (t & 15)];
  u16* Ob = attT + (size_t)b * 262144;
  for (int ch = 0; ch < 32; ++ch) {
    int idx = ch * 256 + t;
    int r = idx & 15, j = idx >> 4;
    float a = __expf(sE[r * 516 + j] - sM[r]) * sS[r];
    Ob[(size_t)j * 512 + i0 + r] = f2h(a);
    float part = a * vbr;
    for (int off = 8; off; off >>= 1) part += __shfl_xor(part, off);
    if (r == 0) atomicAdd(&beta[b * 512 + j], part);
  }
}

// W[b][c][o] = sum_x attT[b][c][x] * vwT[o][x]
__global__ __launch_bounds__(256) void wgemm_kernel(const u16* __restrict__ attT, const u16* __restrict__ vwT,
                                                    u16* __restrict__ W) {
  __shared__ u16 sA[64 * LDST], sB[64 * LDST];
  int ct = blockIdx.x >> 3, ot = blockIdx.x & 7, b = blockIdx.y;
  f32x4 acc[2][2];
#pragma unroll
  for (int i = 0; i < 2; ++i)
#pragma unroll
    for (int j = 0; j < 2; ++j) acc[i][j] = (f32x4){0.f, 0.f, 0.f, 0.f};
  gemm_core<2, 2, false>(attT + (size_t)b * 262144 + (size_t)ct * 64 * 512, 512,
                         vwT + (size_t)ot * 64 * 512, 512, 16, sA, sB, acc);

  const int t = threadIdx.x, lane = t & 63, wave = t >> 6;
  const int wm = wave >> 1, wn = wave & 1, m16 = lane & 15, q4 = lane >> 4;
  u16* O = W + (size_t)b * 262144 + (size_t)(ct * 64) * 512 + ot * 64;
#pragma unroll
  for (int i = 0; i < 2; ++i)
#pragma unroll
    for (int j = 0; j < 2; ++j)
#pragma unroll
      for (int r = 0; r < 4; ++r) {
        int row = wm * 32 + i * 16 + q4 * 4 + r;
        int col = wn * 32 + j * 16 + m16;
        O[(size_t)row * 512 + col] = f2h(acc[i][j][r]);
      }
}

// out[b,c,n] = gamma*(sum_o W[b,c,o]*xh[b,o,n] + beta[b,c]) + x[b,c,n]  (fp32 out)
__global__ __launch_bounds__(256) void outgemm_kernel(const u16* __restrict__ W, const u16* __restrict__ xh,
                                                      const float* __restrict__ x, const float* __restrict__ beta,
                                                      const float* __restrict__ gm, float* __restrict__ out) {
  __shared__ u16 sA[128 * LDST], sB[128 * LDST];
  int nt = blockIdx.x, ct = blockIdx.y, b = blockIdx.z;
  f32x4 acc[4][4];
#pragma unroll
  for (int i = 0; i < 4; ++i)
#pragma unroll
    for (int j = 0; j < 4; ++j) acc[i][j] = (f32x4){0.f, 0.f, 0.f, 0.f};
  gemm_core<4, 4, true>(W + (size_t)b * 262144 + (size_t)ct * 128 * 512, 512,
                        xh + (size_t)b * 2097152 + nt * 128, 4096, 16, sA, sB, acc);

  const int t = threadIdx.x, lane = t & 63, wave = t >> 6;
  const int wm = wave >> 1, wn = wave & 1, m16 = lane & 15, q4 = lane >> 4;
  float g = gm[0];
#pragma unroll
  for (int i = 0; i < 4; ++i)
#pragma unroll
    for (int j = 0; j < 4; ++j)
#pragma unroll
      for (int r = 0; r < 4; ++r) {
        int c = ct * 128 + wm * 64 + i * 16 + q4 * 4 + r;
        int n = nt * 128 + wn * 64 + j * 16 + m16;
        size_t idx = (size_t)b * 2097152 + (size_t)c * 4096 + n;
        out[idx] = g * (acc[i][j][r] + beta[b * 512 + c]) + x[idx];
      }
}

extern "C" void kernel_launch(void* const* d_in, const int* in_sizes, int n_in,
                              void* d_out, int out_size, void* d_ws, size_t ws_size,
                              hipStream_t stream) {
  const float* x  = (const float*)d_in[0];
  const float* pq = (const float*)d_in[1];
  const float* kw = (const float*)d_in[2];
  const float* kb = (const float*)d_in[3];
  const float* vw = (const float*)d_in[4];
  const float* vb = (const float*)d_in[5];
  const float* gm = (const float*)d_in[6];
  float* out = (float*)d_out;

  // workspace: 53 MB + 32 KB
  char* ws = (char*)d_ws;
  u16*   xh   = (u16*)(ws);                            // [0,32M)  fp16 x, live to end
  u16*   qh   = (u16*)(ws + (32ull << 20));            // [32,36M)
  u16*   Sh   = (u16*)(ws + (36ull << 20));            // [36,40M) reused as W after egemm
  u16*   W    = (u16*)(ws + (36ull << 20));
  float* E    = (float*)(ws + (40ull << 20));          // [40,48M) fp32
  u16*   attT = (u16*)(ws + (48ull << 20));            // [48,52M)
  u16*   kwh  = (u16*)(ws + (52ull << 20));            // 512K
  u16*   vwT  = (u16*)(ws + (52ull << 20) + 524288);   // 512K
  char*  sm   = ws + (53ull << 20);                    // small region
  float* qs   = (float*)(sm);
  float* beta = (float*)(sm + 4096);                   // 16K

  cvt_x_kernel<<<dim3(8192), 256, 0, stream>>>(x, xh);
  cvt_q_kernel<<<dim3(512), 256, 0, stream>>>(pq, qh, qs);
  prep_kernel<<<dim3(385), 256, 0, stream>>>(vw, vwT, kw, kwh, beta);
  sgemm_kernel<<<dim3(64, 8), 256, 0, stream>>>(qh, xh, Sh);
  egemm_kernel<<<dim3(64, 8), 256, 0, stream>>>(kwh, Sh, E);
  softmax_kernel<<<dim3(32, 8), 256, 0, stream>>>(E, qs, kb, vb, attT, beta);
  wgemm_kernel<<<dim3(64, 8), 256, 0, stream>>>(attT, vwT, W);
  outgemm_kernel<<<dim3(32, 4, 8), 256, 0, stream>>>(W, xh, x, beta, gm, out);
}